// Round 14
// baseline (286.576 us; speedup 1.0000x reference)
//
#include <hip/hip_runtime.h>
#include <hip/hip_bf16.h>

#define B_ 8
#define E_ 2048
#define N_ 2048
#define F_ 128

#define BM 64      // hyperedge rows per block (4 m-tiles of 16)
#define MT 4       // m-tiles
#define BK 64      // K chunk (elements) -> 32 iterations
#define MP 136     // msg LDS pitch

using bf16x8 = __bf16 __attribute__((ext_vector_type(8)));
using fx4    = float __attribute__((ext_vector_type(4)));

// ---------------- prep: node [B][N][F] f32 -> nodeT [B][F][N] bf16 ----------------
__global__ __launch_bounds__(256) void prep_node(const float* __restrict__ node,
                                                 __bf16* __restrict__ nodeT) {
    const int bid = blockIdx.x;          // 512 blocks
    const int b   = bid & 7;
    const int n0  = (bid >> 3) * 32;
    const int t   = threadIdx.x;
    const int f   = t & 127;
    const int nb  = n0 + (t >> 7) * 16;

    const float* src = node + ((size_t)b * N_ + nb) * F_ + f;
    __bf16 h[16];
#pragma unroll
    for (int i = 0; i < 16; ++i)
        h[i] = (__bf16)src[(size_t)i * F_];

    __bf16* dst = nodeT + ((size_t)b * F_ + f) * N_ + nb;
    *(uint4*)&dst[0] = *(const uint4*)&h[0];
    *(uint4*)&dst[8] = *(const uint4*)&h[8];
}

// ---------------- main: pure-register K-loop — no LDS, no barriers ----------------
__global__ __launch_bounds__(256, 1) void v2h_main(const float* __restrict__ adj,
                                                   const __bf16* __restrict__ nodeT,
                                                   const float* __restrict__ W,
                                                   const float* __restrict__ bias,
                                                   float* __restrict__ out) {
    __shared__ float normS[BM];                      // 256 B
    __shared__ __align__(16) __bf16 Ms[BM * MP];     // 17.4 KB

    const int t    = threadIdx.x;
    const int bid  = blockIdx.x;
    const int b    = bid & 7;            // batch -> XCD L2 locality for nodeT[b]
    const int e0   = (bid >> 3) * BM;
    const int w    = t >> 6;             // wave id = f-group (32 cols)
    const int lane = t & 63;
    const int l15  = lane & 15;
    const int quad = lane >> 4;

    // A: per-thread row pointers (4 m-tiles), base k = quad*8
    const float* aP[MT];
#pragma unroll
    for (int mt = 0; mt < MT; ++mt)
        aP[mt] = adj + ((size_t)b * E_ + e0 + mt * 16 + l15) * N_ + quad * 8;
    // B: per-thread f-row pointers (2 f-tiles), base k = quad*8
    const __bf16* bP[2];
#pragma unroll
    for (int ft = 0; ft < 2; ++ft)
        bP[ft] = nodeT + (size_t)b * F_ * N_
               + (size_t)(w * 32 + ft * 16 + l15) * N_ + quad * 8;

    auto cvt8 = [](float4 v0, float4 v1) -> unsigned {
        unsigned m = 0;
        m |= (v0.x == -1.f) ? 1u   : 0u;
        m |= (v0.y == -1.f) ? 2u   : 0u;
        m |= (v0.z == -1.f) ? 4u   : 0u;
        m |= (v0.w == -1.f) ? 8u   : 0u;
        m |= (v1.x == -1.f) ? 16u  : 0u;
        m |= (v1.y == -1.f) ? 32u  : 0u;
        m |= (v1.z == -1.f) ? 64u  : 0u;
        m |= (v1.w == -1.f) ? 128u : 0u;
        return m;
    };
    auto unpack = [](unsigned byte) -> bf16x8 {
        union { unsigned u[4]; bf16x8 v; } r;
        r.u[0] = ((byte &   1u) ? 0x3F80u : 0u) | ((byte &   2u) ? 0x3F800000u : 0u);
        r.u[1] = ((byte &   4u) ? 0x3F80u : 0u) | ((byte &   8u) ? 0x3F800000u : 0u);
        r.u[2] = ((byte &  16u) ? 0x3F80u : 0u) | ((byte &  32u) ? 0x3F800000u : 0u);
        r.u[3] = ((byte &  64u) ? 0x3F80u : 0u) | ((byte & 128u) ? 0x3F800000u : 0u);
        return r.v;
    };

    fx4 acc[MT][2] = {};
    int cnt[MT] = {};

    // prefetch registers: iter-m data lives in aR/bR at loop top
    float4 aR[MT][4];                    // [mt][kc*2+half]: k offsets 0,4,32,36
    uint4  bR[2][2];                     // [ft][kc]
#pragma unroll
    for (int mt = 0; mt < MT; ++mt) {
        aR[mt][0] = *(const float4*)(aP[mt] + 0);
        aR[mt][1] = *(const float4*)(aP[mt] + 4);
        aR[mt][2] = *(const float4*)(aP[mt] + 32);
        aR[mt][3] = *(const float4*)(aP[mt] + 36);
    }
#pragma unroll
    for (int ft = 0; ft < 2; ++ft) {
        bR[ft][0] = *(const uint4*)(bP[ft] + 0);
        bR[ft][1] = *(const uint4*)(bP[ft] + 32);
    }

#pragma unroll
    for (int m = 0; m < 32; ++m) {
        // ---- convert current A regs -> bf16 0/1 fragments + per-row popc ----
        bf16x8 af[MT][2];
#pragma unroll
        for (int mt = 0; mt < MT; ++mt) {
            unsigned b0 = cvt8(aR[mt][0], aR[mt][1]);
            unsigned b1 = cvt8(aR[mt][2], aR[mt][3]);
            cnt[mt] += __popc(b0 | (b1 << 8));
            af[mt][0] = unpack(b0);
            af[mt][1] = unpack(b1);
        }
        // ---- current B regs -> fragments ----
        bf16x8 bf[2][2];
#pragma unroll
        for (int ft = 0; ft < 2; ++ft) {
            bf[ft][0] = *(const bf16x8*)&bR[ft][0];
            bf[ft][1] = *(const bf16x8*)&bR[ft][1];
        }

        // ---- prefetch iter m+1 ----
        if (m < 31) {
            const int ko = (m + 1) * BK;
#pragma unroll
            for (int mt = 0; mt < MT; ++mt) {
                aR[mt][0] = *(const float4*)(aP[mt] + ko + 0);
                aR[mt][1] = *(const float4*)(aP[mt] + ko + 4);
                aR[mt][2] = *(const float4*)(aP[mt] + ko + 32);
                aR[mt][3] = *(const float4*)(aP[mt] + ko + 36);
            }
#pragma unroll
            for (int ft = 0; ft < 2; ++ft) {
                bR[ft][0] = *(const uint4*)(bP[ft] + ko + 0);
                bR[ft][1] = *(const uint4*)(bP[ft] + ko + 32);
            }
        }

        // ---- 16 MFMAs ----
#pragma unroll
        for (int kc = 0; kc < 2; ++kc)
#pragma unroll
            for (int ft = 0; ft < 2; ++ft)
#pragma unroll
                for (int mt = 0; mt < MT; ++mt)
                    acc[mt][ft] = __builtin_amdgcn_mfma_f32_16x16x32_bf16(
                        af[mt][kc], bf[ft][kc], acc[mt][ft], 0, 0, 0);
    }

    // ---- norm: per-row counts; every wave has identical values, wave 0 writes ----
#pragma unroll
    for (int mt = 0; mt < MT; ++mt) {
        float c = (float)cnt[mt];
        c += __shfl_xor(c, 16);
        c += __shfl_xor(c, 32);
        if (w == 0 && quad == 0)
            normS[mt * 16 + l15] = 1.f / fmaxf(c, 1.f);
    }
    __syncthreads();

    // ---- scale by 1/count, write msg bf16 to LDS in [m][f] layout ----
    const int rbase = quad * 4;
    float4 rn[MT];
#pragma unroll
    for (int mt = 0; mt < MT; ++mt)
        rn[mt] = *(const float4*)&normS[mt * 16 + rbase];

#pragma unroll
    for (int ft = 0; ft < 2; ++ft) {
        int fcol = w * 32 + ft * 16 + l15;
#pragma unroll
        for (int mt = 0; mt < MT; ++mt) {
            const float* rr = (const float*)&rn[mt];
#pragma unroll
            for (int r = 0; r < 4; ++r)
                Ms[(mt * 16 + rbase + r) * MP + fcol] = (__bf16)(acc[mt][ft][r] * rr[r]);
        }
    }
    __syncthreads();

    // ---- second GEMM: W read fp32 direct from global (L2-hot), cvt in regs ----
    fx4 acc2[MT][2] = {};
#pragma unroll
    for (int ks = 0; ks < 4; ++ks) {
        bf16x8 afm[MT];
#pragma unroll
        for (int mt = 0; mt < MT; ++mt)
            afm[mt] = *(const bf16x8*)&Ms[(mt * 16 + l15) * MP + ks * 32 + quad * 8];
#pragma unroll
        for (int gt = 0; gt < 2; ++gt) {
            int g = w * 32 + gt * 16 + l15;
            const float* wp = W + (size_t)g * F_ + ks * 32 + quad * 8;
            float4 wa = *(const float4*)wp;
            float4 wb = *(const float4*)(wp + 4);
            bf16x8 wfr;
            wfr[0] = (__bf16)wa.x; wfr[1] = (__bf16)wa.y;
            wfr[2] = (__bf16)wa.z; wfr[3] = (__bf16)wa.w;
            wfr[4] = (__bf16)wb.x; wfr[5] = (__bf16)wb.y;
            wfr[6] = (__bf16)wb.z; wfr[7] = (__bf16)wb.w;
#pragma unroll
            for (int mt = 0; mt < MT; ++mt)
                acc2[mt][gt] = __builtin_amdgcn_mfma_f32_16x16x32_bf16(
                    afm[mt], wfr, acc2[mt][gt], 0, 0, 0);
        }
    }

    // ---- bias + relu + store ----
#pragma unroll
    for (int gt = 0; gt < 2; ++gt) {
        int g = w * 32 + gt * 16 + l15;
        float bb = bias[g];
#pragma unroll
        for (int mt = 0; mt < MT; ++mt) {
#pragma unroll
            for (int r = 0; r < 4; ++r) {
                int e = e0 + mt * 16 + rbase + r;
                float v = acc2[mt][gt][r] + bb;
                out[((size_t)b * E_ + e) * F_ + g] = fmaxf(v, 0.f);
            }
        }
    }
}

extern "C" void kernel_launch(void* const* d_in, const int* in_sizes, int n_in,
                              void* d_out, int out_size, void* d_ws, size_t ws_size,
                              hipStream_t stream) {
    const float* node = (const float*)d_in[0];   // [B,N,F]
    const float* adj  = (const float*)d_in[1];   // [B,E,N]
    const float* W    = (const float*)d_in[2];   // [F,F]
    const float* bias = (const float*)d_in[3];   // [F]
    float* out = (float*)d_out;                  // [B,E,F]

    __bf16* nodeT = (__bf16*)d_ws;               // 8 MB

    prep_node<<<512, 256, 0, stream>>>(node, nodeT);
    v2h_main<<<256, 256, 0, stream>>>(adj, nodeT, W, bias, out);
}